// Round 13
// baseline (271.110 us; speedup 1.0000x reference)
//
#include <hip/hip_runtime.h>
#include <hip/hip_bf16.h>
#include <math.h>

#define NN   50000
#define EE   1600000
#define ETOT (EE + NN)
#define HID  128
#define INF_ 64
#define OUTF 64

// bucketed CSR build (256 coarse buckets -> coalesced ~100B runs)
#define NBK  256    // buckets (contiguous dst ranges)
#define NPB  196    // nodes per bucket (256*196 = 50176 >= NN)
#define CAP  8192   // per-bucket capacity; mean ~6446
#define BBLK 256    // blocks for k_bucket
#define CHUNK ((ETOT + BBLK - 1) / BBLK)   // 6446 edges per block

#define PADX 72     // xbf row stride (ushorts)
#define PADH 136    // hbf row stride (ushorts)

typedef short  short8  __attribute__((ext_vector_type(8)));
typedef float  floatx4 __attribute__((ext_vector_type(4)));
typedef float  floatx2 __attribute__((ext_vector_type(2)));

__device__ __forceinline__ ushort f2b(float f) {
    __hip_bfloat16 h = __float2bfloat16(f);
    return *reinterpret_cast<ushort*>(&h);
}
__device__ __forceinline__ float b2f_lo(uint v) { return __uint_as_float(v << 16); }
__device__ __forceinline__ float b2f_hi(uint v) { return __uint_as_float(v & 0xffff0000u); }

__device__ __forceinline__ float gelu_f(float x) {
    float x2 = x * x;
    float u  = 0.7978845608f * fmaf(0.044715f * x2, x, x);
    u = fminf(u, 40.f);
    float t = __expf(2.f * u);
    return x * t / (t + 1.f);
}

// ---------------- CSR build ----------------
// pack: (b<<24) | (src<<8) | dloc

__global__ __launch_bounds__(1024) void k_bucket(const int* __restrict__ ei,
                                                 int* bcur, int* __restrict__ tmp) {
    __shared__ unsigned sortedv[CHUNK];
    __shared__ int hist[NBK], gbase[NBK], loff[NBK], lcur[NBK];
    int t = threadIdx.x;
    int lo = blockIdx.x * CHUNK;
    int hi = min(lo + CHUNK, ETOT);
    int bsize = hi - lo;
    if (t < NBK) hist[t] = 0;
    __syncthreads();
    for (int i = lo + t; i < hi; i += 1024) {
        int d = (i < EE) ? ei[EE + i] : i - EE;
        atomicAdd(&hist[d / NPB], 1);
    }
    __syncthreads();
    if (t < NBK) {
        int c = hist[t];
        gbase[t] = (c > 0) ? atomicAdd(&bcur[t], c) : 0;
        loff[t] = c;
    }
    __syncthreads();
    for (int d = 1; d < NBK; d <<= 1) {
        int v = (t >= d && t < NBK) ? loff[t - d] : 0;
        __syncthreads();
        if (t < NBK) loff[t] += v;
        __syncthreads();
    }
    if (t < NBK) {
        int ex = loff[t] - hist[t];
        loff[t] = ex;
        lcur[t] = ex;
    }
    __syncthreads();
    for (int i = lo + t; i < hi; i += 1024) {
        unsigned s, d;
        if (i < EE) { s = (unsigned)ei[i]; d = (unsigned)ei[EE + i]; }
        else        { s = d = (unsigned)(i - EE); }
        unsigned b = d / NPB;
        int p = atomicAdd(&lcur[b], 1);
        sortedv[p] = (b << 24) | (s << 8) | (d - b * NPB);
    }
    __syncthreads();
    for (int i = t; i < bsize; i += 1024) {
        unsigned v = sortedv[i];
        unsigned b = v >> 24;
        int pp = gbase[b] + i - loff[b];
        if (pp < CAP) tmp[b * CAP + pp] = (int)(v & 0xFFFFFFu);
    }
}

// one block per bucket; in-block scan of bcur replaces a separate scan kernel
__global__ __launch_bounds__(1024) void k_bucket2csr(const int* __restrict__ tmp,
                                                     const int* __restrict__ bcur,
                                                     int* __restrict__ off,
                                                     int* __restrict__ csr) {
    __shared__ int sE[CAP];
    __shared__ int lcnt[NPB];
    __shared__ int loff[NPB];
    __shared__ int sb[NBK];
    int b = blockIdx.x, t = threadIdx.x;
    int n0    = b * NPB;
    int bsize = min(bcur[b], CAP);
    if (t < NBK) sb[t] = bcur[t];
    __syncthreads();
    for (int d = 1; d < NBK; d <<= 1) {
        int v = (t >= d && t < NBK) ? sb[t - d] : 0;
        __syncthreads();
        if (t < NBK) sb[t] += v;
        __syncthreads();
    }
    int base = sb[b] - bcur[b];
    if (b == 0 && t == 0) off[NN] = ETOT;
    if (t < NPB) lcnt[t] = 0;
    for (int i = t; i < bsize; i += 1024) sE[i] = tmp[b * CAP + i];
    __syncthreads();
    for (int i = t; i < bsize; i += 1024) atomicAdd(&lcnt[sE[i] & 255], 1);
    __syncthreads();
    if (t < NPB) loff[t] = lcnt[t];
    __syncthreads();
    for (int d = 1; d < NPB; d <<= 1) {
        int v = (t >= d && t < NPB) ? loff[t - d] : 0;
        __syncthreads();
        if (t < NPB) loff[t] += v;
        __syncthreads();
    }
    if (t < NPB) {
        int ex = loff[t] - lcnt[t];
        if (n0 + t < NN) off[n0 + t] = base + ex;
        lcnt[t] = ex;
    }
    __syncthreads();
    for (int i = t; i < bsize; i += 1024) {
        int v   = sE[i];
        int pos = base + atomicAdd(&lcnt[v & 255], 1);
        csr[pos] = v >> 8;
    }
}

// ---- combined weight packing + bcur zeroing + csr pad zeroing: one launch ----

__global__ void k_packall(const float* __restrict__ w_in, const float* __restrict__ W1,
                          const float* __restrict__ W2, ushort* __restrict__ Bp1,
                          ushort* __restrict__ BpW1, ushort* __restrict__ BpW2,
                          int* __restrict__ bcur, int* __restrict__ csr) {
    int tid = blockIdx.x * 256 + threadIdx.x;
    if (tid < NBK) bcur[tid] = 0;
    if (tid < 64) csr[ETOT + tid] = 0;   // pad: k_gat reads past o1 unclamped
    const float* W; ushort* dst; int K, id;
    if (tid < 1024)      { W = w_in; dst = Bp1;  K = 64;  id = tid; }
    else if (tid < 3072) { W = W1;   dst = BpW1; K = 128; id = tid - 1024; }
    else if (tid < 5120) { W = W2;   dst = BpW2; K = 128; id = tid - 3072; }
    else return;
    int kst = K >> 5;
    int l = id & 63;
    int s = (id >> 6) % kst;
    int T = id / (kst * 64);
    int m = l & 15, q = l >> 4;
    ushort o[8];
    #pragma unroll
    for (int j = 0; j < 8; ++j)
        o[j] = f2b(W[(s * 32 + q * 8 + j) * 128 + T * 16 + m]);
    uint4 pk;
    pk.x = (unsigned)o[0] | ((unsigned)o[1] << 16);
    pk.y = (unsigned)o[2] | ((unsigned)o[3] << 16);
    pk.z = (unsigned)o[4] | ((unsigned)o[5] << 16);
    pk.w = (unsigned)o[6] | ((unsigned)o[7] << 16);
    reinterpret_cast<uint4*>(dst)[id] = pk;
}

// ---- shared epilogue: stage acc2 (bf16) in LDS, pack fp8 rows, store ----

__device__ __forceinline__ void pack_store_fp8(ushort* hbfw, int l, int n0w, bool active,
                                               uint* __restrict__ hW8) {
    if (!active) return;
    int row = l >> 2, ch = l & 3;
    uint ov[8];
    #pragma unroll
    for (int u = 0; u < 8; ++u) {
        int c0 = ch * 32 + u * 4;
        float f0 = __uint_as_float((uint)hbfw[row * PADH + c0 + 0] << 16);
        float f1 = __uint_as_float((uint)hbfw[row * PADH + c0 + 1] << 16);
        float f2 = __uint_as_float((uint)hbfw[row * PADH + c0 + 2] << 16);
        float f3 = __uint_as_float((uint)hbfw[row * PADH + c0 + 3] << 16);
        int pk = __builtin_amdgcn_cvt_pk_fp8_f32(f0, f1, 0, false);
        pk     = __builtin_amdgcn_cvt_pk_fp8_f32(f2, f3, pk, true);
        ov[u] = (uint)pk;
    }
    uint4* dst = reinterpret_cast<uint4*>(hW8 + (size_t)(n0w + row) * 32 + ch * 8);
    dst[0] = make_uint4(ov[0], ov[1], ov[2], ov[3]);
    dst[1] = make_uint4(ov[4], ov[5], ov[6], ov[7]);
}

// ------- MFMA fused: x@w_in -> +bias -> LN -> GELU -> @W -> fp8 rows + scores -------

__global__ __launch_bounds__(128) void k_infeat(const float* __restrict__ x,
                                                const ushort* __restrict__ Bp1,
                                                const float* __restrict__ bin,
                                                const float* __restrict__ g,
                                                const float* __restrict__ be,
                                                const ushort* __restrict__ Bp2,
                                                const float* __restrict__ asrc,
                                                const float* __restrict__ adst,
                                                uint* __restrict__ hW8,
                                                float* __restrict__ esrc,
                                                float* __restrict__ edst) {
    __shared__ ushort xbf[2][16 * PADX];
    __shared__ ushort hbf[2][16 * PADH];
    int t = threadIdx.x, w = t >> 6, l = t & 63;
    int m = l & 15, q = l >> 4;
    int n0w = blockIdx.x * 32 + w * 16;
    bool active = (n0w < NN);
    int nb = active ? n0w : 0;

    const float4* x4 = reinterpret_cast<const float4*>(x) + (size_t)nb * 16;
    #pragma unroll
    for (int i = 0; i < 4; ++i) {
        int f4 = l + 64 * i;
        int node = f4 >> 4, c4 = f4 & 15;
        float4 v = x4[f4];
        ushort4 pk = { f2b(v.x), f2b(v.y), f2b(v.z), f2b(v.w) };
        *reinterpret_cast<ushort4*>(&xbf[w][node * PADX + c4 * 4]) = pk;
    }
    __syncthreads();

    const short8* B1 = reinterpret_cast<const short8*>(Bp1);
    floatx4 acc1[8];
    #pragma unroll
    for (int T = 0; T < 8; ++T) acc1[T] = (floatx4){0.f, 0.f, 0.f, 0.f};
    #pragma unroll
    for (int s = 0; s < 2; ++s) {
        short8 a = *reinterpret_cast<const short8*>(&xbf[w][m * PADX + s * 32 + q * 8]);
        #pragma unroll
        for (int T = 0; T < 8; ++T) {
            short8 b = B1[(T * 2 + s) * 64 + l];
            acc1[T] = __builtin_amdgcn_mfma_f32_16x16x32_bf16(a, b, acc1[T], 0, 0, 0);
        }
    }

    float bc[8], gc[8], bec[8];
    #pragma unroll
    for (int T = 0; T < 8; ++T) {
        int c = T * 16 + m;
        bc[T] = bin[c]; gc[T] = g[c]; bec[T] = be[c];
    }
    #pragma unroll
    for (int j = 0; j < 4; ++j) {
        float s1 = 0.f, s2 = 0.f;
        #pragma unroll
        for (int T = 0; T < 8; ++T) {
            float v = acc1[T][j] + bc[T];
            s1 += v; s2 = fmaf(v, v, s2);
        }
        #pragma unroll
        for (int mk = 1; mk < 16; mk <<= 1) {
            s1 += __shfl_xor(s1, mk, 64);
            s2 += __shfl_xor(s2, mk, 64);
        }
        float mu = s1 * (1.f / 128.f);
        float var = s2 * (1.f / 128.f) - mu * mu;
        float rs = rsqrtf(var + 1e-5f);
        #pragma unroll
        for (int T = 0; T < 8; ++T) {
            float v = acc1[T][j] + bc[T];
            float y = (v - mu) * rs * gc[T] + bec[T];
            hbf[w][(q * 4 + j) * PADH + T * 16 + m] = f2b(gelu_f(y));
        }
    }
    __syncthreads();

    const short8* B2 = reinterpret_cast<const short8*>(Bp2);
    floatx4 acc2[8];
    #pragma unroll
    for (int T = 0; T < 8; ++T) acc2[T] = (floatx4){0.f, 0.f, 0.f, 0.f};
    #pragma unroll
    for (int s = 0; s < 4; ++s) {
        short8 a = *reinterpret_cast<const short8*>(&hbf[w][m * PADH + s * 32 + q * 8]);
        #pragma unroll
        for (int T = 0; T < 8; ++T) {
            short8 b = B2[(T * 4 + s) * 64 + l];
            acc2[T] = __builtin_amdgcn_mfma_f32_16x16x32_bf16(a, b, acc2[T], 0, 0, 0);
        }
    }

    __syncthreads();
    #pragma unroll
    for (int j = 0; j < 4; ++j)
        #pragma unroll
        for (int T = 0; T < 8; ++T)
            hbf[w][(q * 4 + j) * PADH + T * 16 + m] = f2b(acc2[T][j]);
    __syncthreads();
    pack_store_fp8(hbf[w], l, n0w, active, hW8);

    float as_[8], ad_[8];
    #pragma unroll
    for (int T = 0; T < 8; ++T) {
        int c = T * 16 + m;
        as_[T] = asrc[c]; ad_[T] = adst[c];
    }
    #pragma unroll
    for (int j = 0; j < 4; ++j) {
        #pragma unroll
        for (int h = 0; h < 4; ++h) {
            float v1 = fmaf(acc2[2 * h][j], as_[2 * h], acc2[2 * h + 1][j] * as_[2 * h + 1]);
            float v2 = fmaf(acc2[2 * h][j], ad_[2 * h], acc2[2 * h + 1][j] * ad_[2 * h + 1]);
            #pragma unroll
            for (int mk = 1; mk < 16; mk <<= 1) {
                v1 += __shfl_xor(v1, mk, 64);
                v2 += __shfl_xor(v2, mk, 64);
            }
            if (m == 0 && active) {
                esrc[(n0w + q * 4 + j) * 4 + h] = v1;
                edst[(n0w + q * 4 + j) * 4 + h] = v2;
            }
        }
    }
}

// ------- MFMA fused layer-2 (bf16 input): LN -> GELU -> @W2 -> fp8 rows + scores -------

__global__ __launch_bounds__(128) void k_feat(const ushort* __restrict__ hinb,
                                              const float* __restrict__ g,
                                              const float* __restrict__ be,
                                              const ushort* __restrict__ Bp2,
                                              const float* __restrict__ asrc,
                                              const float* __restrict__ adst,
                                              uint* __restrict__ hW8,
                                              float* __restrict__ esrc,
                                              float* __restrict__ edst) {
    __shared__ ushort hbf[2][16 * PADH];
    int t = threadIdx.x, w = t >> 6, l = t & 63;
    int m = l & 15, q = l >> 4;
    int n0w = blockIdx.x * 32 + w * 16;
    bool active = (n0w < NN);
    int nb = active ? n0w : 0;

    const float4* g4  = reinterpret_cast<const float4*>(g);
    const float4* be4 = reinterpret_cast<const float4*>(be);
    #pragma unroll
    for (int i = 0; i < 4; ++i) {
        int s = l + 64 * i;
        int node = s >> 4, c8 = s & 15;
        uint4 v = *reinterpret_cast<const uint4*>(hinb + (size_t)(nb + node) * HID + c8 * 8);
        float f[8] = { b2f_lo(v.x), b2f_hi(v.x), b2f_lo(v.y), b2f_hi(v.y),
                       b2f_lo(v.z), b2f_hi(v.z), b2f_lo(v.w), b2f_hi(v.w) };
        float s1 = 0.f, s2 = 0.f;
        #pragma unroll
        for (int j = 0; j < 8; ++j) { s1 += f[j]; s2 = fmaf(f[j], f[j], s2); }
        #pragma unroll
        for (int mk = 1; mk < 16; mk <<= 1) {
            s1 += __shfl_xor(s1, mk, 16);
            s2 += __shfl_xor(s2, mk, 16);
        }
        float mu = s1 * (1.f / 128.f);
        float var = s2 * (1.f / 128.f) - mu * mu;
        float rs = rsqrtf(var + 1e-5f);
        float4 gg0 = g4[c8 * 2], gg1 = g4[c8 * 2 + 1];
        float4 bb0 = be4[c8 * 2], bb1 = be4[c8 * 2 + 1];
        float gv[8] = {gg0.x, gg0.y, gg0.z, gg0.w, gg1.x, gg1.y, gg1.z, gg1.w};
        float bv[8] = {bb0.x, bb0.y, bb0.z, bb0.w, bb1.x, bb1.y, bb1.z, bb1.w};
        ushort4 p0, p1;
        p0.x = f2b(gelu_f((f[0] - mu) * rs * gv[0] + bv[0]));
        p0.y = f2b(gelu_f((f[1] - mu) * rs * gv[1] + bv[1]));
        p0.z = f2b(gelu_f((f[2] - mu) * rs * gv[2] + bv[2]));
        p0.w = f2b(gelu_f((f[3] - mu) * rs * gv[3] + bv[3]));
        p1.x = f2b(gelu_f((f[4] - mu) * rs * gv[4] + bv[4]));
        p1.y = f2b(gelu_f((f[5] - mu) * rs * gv[5] + bv[5]));
        p1.z = f2b(gelu_f((f[6] - mu) * rs * gv[6] + bv[6]));
        p1.w = f2b(gelu_f((f[7] - mu) * rs * gv[7] + bv[7]));
        *reinterpret_cast<ushort4*>(&hbf[w][node * PADH + c8 * 8])     = p0;
        *reinterpret_cast<ushort4*>(&hbf[w][node * PADH + c8 * 8 + 4]) = p1;
    }
    __syncthreads();

    const short8* B2 = reinterpret_cast<const short8*>(Bp2);
    floatx4 acc2[8];
    #pragma unroll
    for (int T = 0; T < 8; ++T) acc2[T] = (floatx4){0.f, 0.f, 0.f, 0.f};
    #pragma unroll
    for (int s = 0; s < 4; ++s) {
        short8 a = *reinterpret_cast<const short8*>(&hbf[w][m * PADH + s * 32 + q * 8]);
        #pragma unroll
        for (int T = 0; T < 8; ++T) {
            short8 b = B2[(T * 4 + s) * 64 + l];
            acc2[T] = __builtin_amdgcn_mfma_f32_16x16x32_bf16(a, b, acc2[T], 0, 0, 0);
        }
    }

    __syncthreads();
    #pragma unroll
    for (int j = 0; j < 4; ++j)
        #pragma unroll
        for (int T = 0; T < 8; ++T)
            hbf[w][(q * 4 + j) * PADH + T * 16 + m] = f2b(acc2[T][j]);
    __syncthreads();
    pack_store_fp8(hbf[w], l, n0w, active, hW8);

    float as_[8], ad_[8];
    #pragma unroll
    for (int T = 0; T < 8; ++T) {
        int c = T * 16 + m;
        as_[T] = asrc[c]; ad_[T] = adst[c];
    }
    #pragma unroll
    for (int j = 0; j < 4; ++j) {
        #pragma unroll
        for (int h = 0; h < 4; ++h) {
            float v1 = fmaf(acc2[2 * h][j], as_[2 * h], acc2[2 * h + 1][j] * as_[2 * h + 1]);
            float v2 = fmaf(acc2[2 * h][j], ad_[2 * h], acc2[2 * h + 1][j] * ad_[2 * h + 1]);
            #pragma unroll
            for (int mk = 1; mk < 16; mk <<= 1) {
                v1 += __shfl_xor(v1, mk, 64);
                v2 += __shfl_xor(v2, mk, 64);
            }
            if (m == 0 && active) {
                esrc[(n0w + q * 4 + j) * 4 + h] = v1;
                edst[(n0w + q * 4 + j) * 4 + h] = v2;
            }
        }
    }
}

// ------- GAT aggregate v10: one wave per node, 8 slots x 8 col-groups (uint4 rows) -------
// Lane l: slot=l>>3 (edge within 8-edge batch), q8=l&7 (cols 16*q8..16*q8+15), head=q8>>1.
// Per body: 1 row load (16B), 1 csr, 1 esrc, 1 exp, 8 cvt + 8 pk_fma -> ~5 inst/edge.
// Rotation depth 2 rows in flight; csr 3 batches ahead. 32-bit offsets (SGPR-base addr).

__global__ __launch_bounds__(256) void k_gat(const uint* __restrict__ hW8,
                                             const float* __restrict__ esrc,
                                             const float* __restrict__ edst,
                                             const int* __restrict__ off,
                                             const int* __restrict__ csr,
                                             const float* __restrict__ bg,
                                             ushort* __restrict__ outb) {
    int t = threadIdx.x;
    int wv = t >> 6, l = t & 63;
    int slot = l >> 3;
    int q8   = l & 7;
    int hq   = q8 >> 1;
    int n = blockIdx.x * 4 + wv;       // grid = NN/4 exactly
    int o0 = off[n], o1 = off[n + 1];
    float ednh = edst[n * 4 + hq];
    const uint4* hw4 = reinterpret_cast<const uint4*>(hW8);
    floatx2 a[8];
    #pragma unroll
    for (int j = 0; j < 8; ++j) a[j] = (floatx2){0.f, 0.f};
    float dsum = 0.f;
    int nIter = (o1 - o0 + 7) >> 3;    // 8 edges per body
    int e = o0 + slot;

    // prologue (csr padded with zeros past ETOT: no clamps)
    int srcA = csr[e];
    int srcB = csr[e + 8];
    int srcC = csr[e + 16];
    float esA = esrc[srcA * 4 + hq];
    uint4 rA = hw4[srcA * 8 + q8];     // 32-bit offset: s-base + v-offset addressing
    uint4 rB = hw4[srcB * 8 + q8];

    for (int it = 0; it < nIter; ++it) {
        uint4 rC   = hw4[srcC * 8 + q8];        // row(it+2)
        float esN  = esrc[srcB * 4 + hq];       // es(it+1)
        int   srcD = csr[e + 24];               // src(it+3)
        float ea = esA + ednh; ea = fmaxf(ea, 0.2f * ea);
        float w  = (e < o1) ? __expf(ea) : 0.f;
        floatx2 w2 = {w, w};
        a[0] += w2 * __builtin_amdgcn_cvt_pk_f32_fp8(rA.x, false);
        a[1] += w2 * __builtin_amdgcn_cvt_pk_f32_fp8(rA.x, true);
        a[2] += w2 * __builtin_amdgcn_cvt_pk_f32_fp8(rA.y, false);
        a[3] += w2 * __builtin_amdgcn_cvt_pk_f32_fp8(rA.y, true);
        a[4] += w2 * __builtin_amdgcn_cvt_pk_f32_fp8(rA.z, false);
        a[5] += w2 * __builtin_amdgcn_cvt_pk_f32_fp8(rA.z, true);
        a[6] += w2 * __builtin_amdgcn_cvt_pk_f32_fp8(rA.w, false);
        a[7] += w2 * __builtin_amdgcn_cvt_pk_f32_fp8(rA.w, true);
        dsum += w;
        e += 8;
        rA = rB; rB = rC;
        srcB = srcC; srcC = srcD;
        esA = esN;
    }
    // reduce across the 8 edge slots (lane bits 3,4,5)
    #pragma unroll
    for (int mk = 8; mk <= 32; mk <<= 1) {
        #pragma unroll
        for (int j = 0; j < 8; ++j) {
            a[j][0] += __shfl_xor(a[j][0], mk, 64);
            a[j][1] += __shfl_xor(a[j][1], mk, 64);
        }
        dsum += __shfl_xor(dsum, mk, 64);
    }
    if (l < 8) {                        // slot-0 lanes hold all 8 col groups
        float inv = 1.0f / dsum;
        float v[16];
        #pragma unroll
        for (int j = 0; j < 8; ++j) {
            v[2 * j]     = a[j][0] * inv + bg[l * 16 + 2 * j];
            v[2 * j + 1] = a[j][1] * inv + bg[l * 16 + 2 * j + 1];
        }
        uint4 o0v, o1v;
        o0v.x = (uint)f2b(v[0])  | ((uint)f2b(v[1])  << 16);
        o0v.y = (uint)f2b(v[2])  | ((uint)f2b(v[3])  << 16);
        o0v.z = (uint)f2b(v[4])  | ((uint)f2b(v[5])  << 16);
        o0v.w = (uint)f2b(v[6])  | ((uint)f2b(v[7])  << 16);
        o1v.x = (uint)f2b(v[8])  | ((uint)f2b(v[9])  << 16);
        o1v.y = (uint)f2b(v[10]) | ((uint)f2b(v[11]) << 16);
        o1v.z = (uint)f2b(v[12]) | ((uint)f2b(v[13]) << 16);
        o1v.w = (uint)f2b(v[14]) | ((uint)f2b(v[15]) << 16);
        uint4* op = reinterpret_cast<uint4*>(outb + (size_t)n * HID + l * 16);
        op[0] = o0v;
        op[1] = o1v;
    }
}

// ------- output linear (bf16 input): 32 nodes/block, 4 nodes x 4 cols/thread -------

__global__ __launch_bounds__(128) void k_out(const ushort* __restrict__ hb,
                                             const float* __restrict__ w,
                                             const float* __restrict__ b,
                                             float* __restrict__ out) {
    __shared__ __align__(16) float hr[32 * 132];
    int t = threadIdx.x, n0 = blockIdx.x * 32;
    float4* hr4 = reinterpret_cast<float4*>(hr);
    #pragma unroll
    for (int i = 0; i < 4; ++i) {
        int s = t + 128 * i;
        int node = s >> 4, c8 = s & 15;
        uint4 v = *reinterpret_cast<const uint4*>(hb + (size_t)(n0 + node) * HID + c8 * 8);
        float4 lo = { b2f_lo(v.x), b2f_hi(v.x), b2f_lo(v.y), b2f_hi(v.y) };
        float4 hi = { b2f_lo(v.z), b2f_hi(v.z), b2f_lo(v.w), b2f_hi(v.w) };
        hr4[node * 33 + c8 * 2]     = lo;
        hr4[node * 33 + c8 * 2 + 1] = hi;
    }
    __syncthreads();
    int cg = t & 15, ng = t >> 4;
    const float4* w4 = reinterpret_cast<const float4*>(w);
    float4 bb = reinterpret_cast<const float4*>(b)[cg];
    float4 acc[4] = {bb, bb, bb, bb};
    for (int k4 = 0; k4 < 32; ++k4) {
        float4 w0 = w4[(k4 * 4 + 0) * 16 + cg];
        float4 w1 = w4[(k4 * 4 + 1) * 16 + cg];
        float4 w2 = w4[(k4 * 4 + 2) * 16 + cg];
        float4 w3 = w4[(k4 * 4 + 3) * 16 + cg];
        #pragma unroll
        for (int r = 0; r < 4; ++r) {
            float4 hv = hr4[(ng * 4 + r) * 33 + k4];
            acc[r].x = fmaf(hv.x, w0.x, fmaf(hv.y, w1.x, fmaf(hv.z, w2.x, fmaf(hv.w, w3.x, acc[r].x))));
            acc[r].y = fmaf(hv.x, w0.y, fmaf(hv.y, w1.y, fmaf(hv.z, w2.y, fmaf(hv.w, w3.y, acc[r].y))));
            acc[r].z = fmaf(hv.x, w0.z, fmaf(hv.y, w1.z, fmaf(hv.z, w2.z, fmaf(hv.w, w3.z, acc[r].z))));
            acc[r].w = fmaf(hv.x, w0.w, fmaf(hv.y, w1.w, fmaf(hv.z, w2.w, fmaf(hv.w, w3.w, acc[r].w))));
        }
    }
    float4* o4 = reinterpret_cast<float4*>(out) + (size_t)n0 * 16;
    #pragma unroll
    for (int r = 0; r < 4; ++r) {
        if (n0 + ng * 4 + r < NN)
            o4[(ng * 4 + r) * 16 + cg] = acc[r];
    }
}

extern "C" void kernel_launch(void* const* d_in, const int* in_sizes, int n_in,
                              void* d_out, int out_size, void* d_ws, size_t ws_size,
                              hipStream_t stream) {
    const float* x    = (const float*)d_in[0];
    const int*   ei   = (const int*)  d_in[1];
    const float* w_in = (const float*)d_in[2];
    const float* b_in = (const float*)d_in[3];
    const float* g1   = (const float*)d_in[4];
    const float* be1  = (const float*)d_in[5];
    const float* W1   = (const float*)d_in[6];
    const float* as1  = (const float*)d_in[7];
    const float* ad1  = (const float*)d_in[8];
    const float* bg1  = (const float*)d_in[9];
    const float* g2   = (const float*)d_in[10];
    const float* be2  = (const float*)d_in[11];
    const float* W2   = (const float*)d_in[12];
    const float* as2  = (const float*)d_in[13];
    const float* ad2  = (const float*)d_in[14];
    const float* bg2  = (const float*)d_in[15];
    const float* w_o  = (const float*)d_in[16];
    const float* b_o  = (const float*)d_in[17];
    float* out = (float*)d_out;

    char* p = (char*)d_ws;
    auto take = [&](size_t bytes) {
        void* r = p;
        p += (bytes + 255) & ~(size_t)255;
        return r;
    };
    ushort* gout  = (ushort*)take((size_t)(NN + 32) * HID * 2);  // bf16 (+pad rows)
    ushort* h2    = (ushort*)take((size_t)(NN + 32) * HID * 2);  // bf16
    uint*   hW8   = (uint*)take((size_t)NN * HID);               // fp8 gather table
    float*  esrc  = (float*)take((size_t)NN * 4 * 4);
    float*  edst  = (float*)take((size_t)NN * 4 * 4);
    int*    off   = (int*)take((size_t)(NN + 1) * 4);
    int*    csr   = (int*)take((size_t)(ETOT + 64) * 4);         // +64 zeroed pad
    int*    tmp   = (int*)take((size_t)NBK * CAP * 4);
    int*    bcur  = (int*)take((size_t)NBK * 4);
    ushort* Bp1   = (ushort*)take((size_t)1024 * 16);
    ushort* BpW1  = (ushort*)take((size_t)2048 * 16);
    ushort* BpW2  = (ushort*)take((size_t)2048 * 16);

    k_packall   <<<20, 256, 0, stream>>>(w_in, W1, W2, Bp1, BpW1, BpW2, bcur, csr);
    k_bucket    <<<BBLK, 1024, 0, stream>>>(ei, bcur, tmp);
    k_bucket2csr<<<NBK, 1024, 0, stream>>>(tmp, bcur, off, csr);

    int gfeat = (NN + 31) / 32;
    k_infeat<<<gfeat, 128, 0, stream>>>(x, Bp1, b_in, g1, be1, BpW1, as1, ad1, hW8, esrc, edst);
    k_gat   <<<NN / 4, 256, 0, stream>>>(hW8, esrc, edst, off, csr, bg1, gout);
    k_feat  <<<gfeat, 128, 0, stream>>>(gout, g2, be2, BpW2, as2, ad2, hW8, esrc, edst);
    k_gat   <<<NN / 4, 256, 0, stream>>>(hW8, esrc, edst, off, csr, bg2, h2);
    k_out   <<<(NN + 31) / 32, 128, 0, stream>>>(h2, w_o, b_o, out);
}